// Round 1
// baseline (101.207 us; speedup 1.0000x reference)
//
#include <hip/hip_runtime.h>

// Problem constants (from reference setup_inputs)
constexpr int B = 8, C = 3, H = 544, W = 960;
constexpr int KH = 3, KW = 3;
constexpr int HW = H * W;        // 522240
constexpr int WQ = W / 4;        // 240 float4-quads per row
constexpr int NK = C * KH * KW;  // 27 filter planes

__global__ __launch_bounds__(256) void DynFilter_kernel(
    const float* __restrict__ x,     // [B, C, H, W]
    const float* __restrict__ filt,  // [B, 27, H, W]
    float* __restrict__ out)         // [B, 1, H, W]
{
    int tid = blockIdx.x * blockDim.x + threadIdx.x;
    constexpr int total = B * H * WQ;
    if (tid >= total) return;

    int wq = tid % WQ;
    int t  = tid / WQ;
    int h  = t % H;
    int b  = t / H;
    int w0 = wq * 4;

    float4 acc = make_float4(0.f, 0.f, 0.f, 0.f);

    const float* fbase = filt + (size_t)b * NK * HW + (size_t)h * W + w0;

    #pragma unroll
    for (int c = 0; c < C; ++c) {
        const float* xc = x + ((size_t)b * C + c) * HW;
        #pragma unroll
        for (int i = 0; i < KH; ++i) {
            int hr = h + i - 1;
            bool vh = (unsigned)hr < (unsigned)H;
            // xv[k] holds x column (w0 - 1 + k), k = 0..5
            float xv0, xv1, xv2, xv3, xv4, xv5;
            if (vh) {
                const float* xr = xc + (size_t)hr * W + w0;  // 16B aligned
                float4 m = *reinterpret_cast<const float4*>(xr);
                xv1 = m.x; xv2 = m.y; xv3 = m.z; xv4 = m.w;
                xv0 = (w0 > 0)      ? xr[-1] : 0.f;
                xv5 = (w0 + 4 < W)  ? xr[4]  : 0.f;
            } else {
                xv0 = xv1 = xv2 = xv3 = xv4 = xv5 = 0.f;
            }
            float xv[6] = {xv0, xv1, xv2, xv3, xv4, xv5};
            #pragma unroll
            for (int j = 0; j < KW; ++j) {
                int k = c * (KH * KW) + i * KW + j;
                float4 f = *reinterpret_cast<const float4*>(fbase + (size_t)k * HW);
                acc.x += xv[j]     * f.x;
                acc.y += xv[j + 1] * f.y;
                acc.z += xv[j + 2] * f.z;
                acc.w += xv[j + 3] * f.w;
            }
        }
    }

    *reinterpret_cast<float4*>(out + (size_t)b * HW + (size_t)h * W + w0) = acc;
}

extern "C" void kernel_launch(void* const* d_in, const int* in_sizes, int n_in,
                              void* d_out, int out_size, void* d_ws, size_t ws_size,
                              hipStream_t stream) {
    const float* x    = (const float*)d_in[0];
    const float* filt = (const float*)d_in[1];
    float* out        = (float*)d_out;

    constexpr int total  = B * H * WQ;           // 1,044,480 threads
    constexpr int block  = 256;
    constexpr int blocks = (total + block - 1) / block;  // 4080

    DynFilter_kernel<<<blocks, block, 0, stream>>>(x, filt, out);
}